// Round 12
// baseline (131.081 us; speedup 1.0000x reference)
//
#include <hip/hip_runtime.h>
#include <hip/hip_fp16.h>
#include <stdint.h>
#include <stddef.h>

#define N 2048
#define KMX 192
#define NTH 1024

typedef _Float16 f16x2 __attribute__((ext_vector_type(2)));
typedef _Float16 f16x4 __attribute__((ext_vector_type(4)));

#if defined(__has_builtin)
#if __has_builtin(__builtin_amdgcn_fdot2)
#define HAS_FDOT2 1
#endif
#endif

__device__ __forceinline__ f16x2 bch2(unsigned u) { return __builtin_bit_cast(f16x2, u); }
__device__ __forceinline__ unsigned packh2(float a, float b) {
  unsigned ua = (unsigned)__half_as_ushort(__float2half(a));
  unsigned ub = (unsigned)__half_as_ushort(__float2half(b));
  return ua | (ub << 16);
}
__device__ __forceinline__ float dot2acc(unsigned c, unsigned y, float acc) {
#ifdef HAS_FDOT2
  return __builtin_amdgcn_fdot2(bch2(c), bch2(y), acc, false);
#else
  f16x2 cv = bch2(c), yv = bch2(y);
  acc = fmaf((float)cv[0], (float)yv[0], acc);
  acc = fmaf((float)cv[1], (float)yv[1], acc);
  return acc;
#endif
}

// ---------------- Threefry-2x32, JAX-compatible (20 rounds) ----------------
__device__ __forceinline__ void tfround(unsigned &x0, unsigned &x1, const int d) {
  x0 += x1;
  x1 = (x1 << d) | (x1 >> (32 - d));
  x1 ^= x0;
}

__device__ __forceinline__ uint2 tf2x32(unsigned k0, unsigned k1, unsigned c0, unsigned c1) {
  unsigned ks2 = k0 ^ k1 ^ 0x1BD11BDAu;
  unsigned x0 = c0 + k0, x1 = c1 + k1;
  tfround(x0,x1,13); tfround(x0,x1,15); tfround(x0,x1,26); tfround(x0,x1,6);
  x0 += k1;  x1 += ks2 + 1u;
  tfround(x0,x1,17); tfround(x0,x1,29); tfround(x0,x1,16); tfround(x0,x1,24);
  x0 += ks2; x1 += k0 + 2u;
  tfround(x0,x1,13); tfround(x0,x1,15); tfround(x0,x1,26); tfround(x0,x1,6);
  x0 += k0;  x1 += k1 + 3u;
  tfround(x0,x1,17); tfround(x0,x1,29); tfround(x0,x1,16); tfround(x0,x1,24);
  x0 += k1;  x1 += ks2 + 4u;
  tfround(x0,x1,13); tfround(x0,x1,15); tfround(x0,x1,26); tfround(x0,x1,6);
  x0 += ks2; x1 += k0 + 5u;
  uint2 r; r.x = x0; r.y = x1;
  return r;
}

// JAX uniform [0,1): (bits>>9 | 0x3f800000) bitcast - 1.0f  (exact)
__device__ __forceinline__ float u01(unsigned bits) {
  return __uint_as_float((bits >> 9) | 0x3f800000u) - 1.0f;
}

// ---------------- Kernel 1: Bernoulli selection + key derivation ----------------
__global__ void k_select(const float* __restrict__ e, const int* __restrict__ seedp,
                         int* __restrict__ hdr, int* __restrict__ sel) {
  __shared__ unsigned kx0, kx1;
  __shared__ int cnt_s[256];
  __shared__ int pre_s[256];
  const int tid = threadIdx.x;
  if (tid == 0) {
    unsigned seed = (unsigned)seedp[0];
    uint2 kidx  = tf2x32(0u, seed, 0u, 0u);
    uint2 kloop = tf2x32(0u, seed, 0u, 1u);
    kx0 = kidx.x; kx1 = kidx.y;
    hdr[2] = (int)kloop.x;
    hdr[3] = (int)kloop.y;
  }
  __syncthreads();
  const unsigned a0 = kx0, a1 = kx1;
  int flags = 0;
  #pragma unroll
  for (int r = 0; r < 8; ++r) {
    const int i = tid * 8 + r;
    uint2 o = tf2x32(a0, a1, 0u, (unsigned)i);
    float u = u01(o.x ^ o.y);
    float ev = e[i];
    float thr = ev / (ev + 1.0f);   // IEEE f32 div, matches XLA bit-exactly
    if (u < thr) flags |= (1 << r);
  }
  cnt_s[tid] = __popc(flags);
  __syncthreads();
  if (tid == 0) {
    int acc = 0;
    for (int t2 = 0; t2 < 256; ++t2) { pre_s[t2] = acc; acc += cnt_s[t2]; }
    hdr[1] = acc;
    hdr[0] = acc < KMX ? acc : KMX;
  }
  __syncthreads();
  int off = pre_s[tid];
  #pragma unroll
  for (int r = 0; r < 8; ++r) {
    if (flags & (1 << r)) {
      if (off < KMX) sel[off] = tid * 8 + r;
      ++off;
    }
  }
}

// ---------------- Kernel 2 (chol path): gather Gh fp16 only (col-major, zero-pad) ----
__global__ void k_gather_h(const float* __restrict__ v, const int* __restrict__ hdr,
                           const int* __restrict__ sel, __half* __restrict__ Gh) {
  const int j = blockIdx.y;
  const int i = blockIdx.x * 256 + threadIdx.x;
  float val = 0.f;
  if (j < hdr[0]) val = v[(size_t)i * N + sel[j]];
  Gh[j * N + i] = __float2half(val);
}

// ---------------- Kernel 2 (fallback path): gather G f32 + Gh fp16 mirror ----
__global__ void k_gather(const float* __restrict__ v, const int* __restrict__ hdr,
                         const int* __restrict__ sel, float* __restrict__ G,
                         __half* __restrict__ Gh) {
  const int j = blockIdx.y;
  const int i = blockIdx.x * 256 + threadIdx.x;
  float val = 0.f;
  if (j < hdr[0]) val = v[(size_t)i * N + sel[j]];
  G[j * N + i] = val;
  Gh[j * N + i] = __float2half(val);
}

// ---------------- Kernel 2b: Gram K = G^T G (fp16 out, f32 accum), 64x64 tiles ----------
__global__ void __launch_bounds__(256)
k_gram(const __half* __restrict__ Gh, const int* __restrict__ hdr,
       __half* __restrict__ Kh) {
  __shared__ __align__(16) __half As[32][64];
  __shared__ __align__(16) __half Bs[32][64];
  const int tid = threadIdx.x;
  const int i0 = blockIdx.y * 64;   // C rows
  const int i1 = blockIdx.x * 64;   // C cols
  const int tr = tid & 15, tc = tid >> 4;
  const int kk = hdr[0];
  int kc = (kk + 31) & ~31;
  if (kc > KMX) kc = KMX;

  float acc[4][4];
  #pragma unroll
  for (int r = 0; r < 4; ++r)
    #pragma unroll
    for (int c = 0; c < 4; ++c) acc[r][c] = 0.f;

  const int jr = tid >> 3, c8 = (tid & 7) * 8;
  for (int j0 = 0; j0 < kc; j0 += 32) {
    *(uint4*)&As[jr][c8] = *(const uint4*)(Gh + (size_t)(j0 + jr) * N + i0 + c8);
    *(uint4*)&Bs[jr][c8] = *(const uint4*)(Gh + (size_t)(j0 + jr) * N + i1 + c8);
    __syncthreads();
    #pragma unroll 8
    for (int k = 0; k < 32; ++k) {
      f16x4 a4 = *(const f16x4*)&As[k][tr * 4];
      f16x4 b4 = *(const f16x4*)&Bs[k][tc * 4];
      #pragma unroll
      for (int r = 0; r < 4; ++r)
        #pragma unroll
        for (int c = 0; c < 4; ++c)
          acc[r][c] = fmaf((float)a4[r], (float)b4[c], acc[r][c]);
    }
    __syncthreads();
  }
  #pragma unroll
  for (int r = 0; r < 4; ++r) {
    const int row = i0 + tr * 4 + r;
    uint2 w;
    w.x = packh2(acc[r][0], acc[r][1]);
    w.y = packh2(acc[r][2], acc[r][3]);
    *(uint2*)(Kh + (size_t)row * N + i1 + tc * 4) = w;
  }
}

// ---------------- Kernel 3: Cholesky-style sequential DPP loop (quad-packed Y) ------
// (R11 structure, byte-identical — the measured/proven production path.)
__global__ void __launch_bounds__(NTH)
k_dpp_chol(const int* __restrict__ hdr, const __half* __restrict__ Kh,
           uint2* __restrict__ YQ, float* __restrict__ out) {
  __shared__ float p_s[N];
  __shared__ uint2 cpack_s[KMX / 4];   // staged fp16 coefficient quads (masked)
  __shared__ float u_s[KMX];
  __shared__ float wsum_s[16];
  __shared__ int item_sh;

  const int tid  = threadIdx.x;
  const int lane = tid & 63;
  const int wave = tid >> 6;
  const int kk    = hdr[0];
  const int kfull = hdr[1];
  const unsigned kl0 = (unsigned)hdr[2];
  const unsigned kl1 = (unsigned)hdr[3];

  const float fill = (kfull == N) ? 1.0f : 0.0f;   // reference: k==n -> all ones
  out[tid] = fill;
  out[tid + NTH] = fill;
  if (kfull == N || kk == 0) return;

  const int i0 = 2 * tid;

  float p0 = (float)Kh[(size_t)i0 * N + i0];
  float p1 = (float)Kh[(size_t)(i0 + 1) * N + i0 + 1];
  p_s[i0]     = p0;
  p_s[i0 + 1] = p1;
  if (tid < KMX) {
    uint2 fk = tf2x32(kl0, kl1, 0u, (unsigned)tid);
    uint2 ob = tf2x32(fk.x, fk.y, 0u, 0u);
    u_s[tid] = u01(ob.x ^ ob.y);
  }
  if (tid == 0) item_sh = N;
  __syncthreads();

  for (int t = 0; t < kk; ++t) {
    float ts = p0 + p1;
    float ws = ts;
    #pragma unroll
    for (int d = 1; d < 64; d <<= 1) {
      float o = __shfl_up(ws, d, 64);
      if (lane >= d) ws += o;
    }
    if (lane == 63) wsum_s[wave] = ws;
    __syncthreads();                                   // (A)
    float wv = (lane < 16) ? wsum_s[lane] : 0.f;
    #pragma unroll
    for (int d = 1; d < 16; d <<= 1) {
      float o = __shfl_up(wv, d, 16);
      if ((lane & 15) >= d) wv += o;
    }
    const float S    = __shfl(wv, 15, 64);
    const float binc = __shfl(wv, wave, 64);
    const float base_wave = binc - wsum_s[wave];
    const float Sinv = 1.0f / S;
    const float u = u_s[t];
    float excl = __shfl_up(ws, 1, 64);
    if (lane == 0) excl = 0.f;
    const float base = base_wave + excl;
    const float c0 = (base + p0) * Sinv;
    const float c1 = (base + ts) * Sinv;
    const bool m0 = (u < c0);
    const bool m1 = (u < c1);
    unsigned long long bal = __ballot(m0 || m1);
    if (bal) {
      int first = (int)__builtin_ctzll(bal);
      if (lane == first) atomicMin(&item_sh, m0 ? i0 : i0 + 1);
    }
    __syncthreads();                                   // (B)
    int item = item_sh;
    if (item >= N) item = 0;                           // argmax(all False) == 0
    if (tid == 0) out[item] = 1.0f;
    if (t == kk - 1) break;                            // reference: m==1 -> no update

    const unsigned kp = *(const unsigned*)(Kh + (size_t)item * N + i0);
    const float rinv = 1.0f / sqrtf(fmaxf(p_s[item], 1e-30f));

    if (tid * 4 < t) {
      uint2 cu = YQ[(size_t)tid * N + item];
      const int rem2 = t - 4 * tid;
      if (rem2 < 4) {
        if (rem2 == 1)      { cu.x &= 0x0000FFFFu; cu.y = 0u; }
        else if (rem2 == 2) { cu.y = 0u; }
        else                { cu.y &= 0x0000FFFFu; }
      }
      cpack_s[tid] = cu;
    }
    if (tid == 0) item_sh = N;
    __syncthreads();                                   // (C)

    {
      const int nq = (t + 3) >> 2;
      float acc0 = 0.f, acc1 = 0.f;
      const uint2* Yp = YQ + i0;
      #pragma unroll 4
      for (int q = 0; q < nq; ++q) {
        uint2 cs = cpack_s[q];
        uint4 yv = *(const uint4*)(Yp + (size_t)q * N);
        acc0 = dot2acc(cs.x, yv.x, acc0);
        acc0 = dot2acc(cs.y, yv.y, acc0);
        acc1 = dot2acc(cs.x, yv.z, acc1);
        acc1 = dot2acc(cs.y, yv.w, acc1);
      }
      f16x2 kv = bch2(kp);
      const float y0 = ((float)kv[0] - acc0) * rinv;
      const float y1 = ((float)kv[1] - acc1) * rinv;
      p0 = fmaxf(p0 - y0 * y0, 0.f);
      p1 = fmaxf(p1 - y1 * y1, 0.f);
      p_s[i0]     = p0;
      p_s[i0 + 1] = p1;
      unsigned short* Ys = (unsigned short*)YQ;
      const int rem = t & 3;
      const size_t eb = ((size_t)(t >> 2) * N + i0) * 4;
      Ys[eb + rem]     = __half_as_ushort(__float2half(y0));
      Ys[eb + 4 + rem] = __half_as_ushort(__float2half(y1));
    }
  }
}

// ---------------- ABLATION PROBES (write to scratch, not d_out) ----------------
// V=1 NOSCAN: dot2 loop removed (staging kept live via asm keep-alive).
// V=2 NOSEL : item = (t*1009)&2047; shfl scans/ballot removed; BARRIERS KEPT.
// Decomposition: SCAN = chol - probe<1>; SEL = chol - probe<2>.
template<int V>
__global__ void __launch_bounds__(NTH)
k_dpp_probe(const int* __restrict__ hdr, const __half* __restrict__ Kh,
            uint2* __restrict__ YQ, float* __restrict__ outp) {
  __shared__ float p_s[N];
  __shared__ uint2 cpack_s[KMX / 4];
  __shared__ float u_s[KMX];
  __shared__ float wsum_s[16];
  __shared__ int item_sh;

  const int tid  = threadIdx.x;
  const int lane = tid & 63;
  const int wave = tid >> 6;
  const int kk    = hdr[0];
  const int kfull = hdr[1];
  const unsigned kl0 = (unsigned)hdr[2];
  const unsigned kl1 = (unsigned)hdr[3];

  const float fill = (kfull == N) ? 1.0f : 0.0f;
  outp[tid] = fill;
  outp[tid + NTH] = fill;
  if (kfull == N || kk == 0) return;

  const int i0 = 2 * tid;

  float p0 = (float)Kh[(size_t)i0 * N + i0];
  float p1 = (float)Kh[(size_t)(i0 + 1) * N + i0 + 1];
  p_s[i0]     = p0;
  p_s[i0 + 1] = p1;
  if (tid < KMX) {
    uint2 fk = tf2x32(kl0, kl1, 0u, (unsigned)tid);
    uint2 ob = tf2x32(fk.x, fk.y, 0u, 0u);
    u_s[tid] = u01(ob.x ^ ob.y);
  }
  if (tid == 0) item_sh = N;
  __syncthreads();

  for (int t = 0; t < kk; ++t) {
    int item;
    if (V == 2) {
      __syncthreads();                                 // (A) kept
      item = (t * 1009) & (N - 1);
      __syncthreads();                                 // (B) kept
      if (tid == 0) outp[item] = 1.0f;
    } else {
      float ts = p0 + p1;
      float ws = ts;
      #pragma unroll
      for (int d = 1; d < 64; d <<= 1) {
        float o = __shfl_up(ws, d, 64);
        if (lane >= d) ws += o;
      }
      if (lane == 63) wsum_s[wave] = ws;
      __syncthreads();                                 // (A)
      float wv = (lane < 16) ? wsum_s[lane] : 0.f;
      #pragma unroll
      for (int d = 1; d < 16; d <<= 1) {
        float o = __shfl_up(wv, d, 16);
        if ((lane & 15) >= d) wv += o;
      }
      const float S    = __shfl(wv, 15, 64);
      const float binc = __shfl(wv, wave, 64);
      const float base_wave = binc - wsum_s[wave];
      const float Sinv = 1.0f / S;
      const float u = u_s[t];
      float excl = __shfl_up(ws, 1, 64);
      if (lane == 0) excl = 0.f;
      const float base = base_wave + excl;
      const float c0 = (base + p0) * Sinv;
      const float c1 = (base + ts) * Sinv;
      const bool m0 = (u < c0);
      const bool m1 = (u < c1);
      unsigned long long bal = __ballot(m0 || m1);
      if (bal) {
        int first = (int)__builtin_ctzll(bal);
        if (lane == first) atomicMin(&item_sh, m0 ? i0 : i0 + 1);
      }
      __syncthreads();                                 // (B)
      item = item_sh;
      if (item >= N) item = 0;
      if (tid == 0) outp[item] = 1.0f;
    }
    if (t == kk - 1) break;

    const unsigned kp = *(const unsigned*)(Kh + (size_t)item * N + i0);
    const float rinv = 1.0f / sqrtf(fmaxf(p_s[item], 1e-30f));

    if (tid * 4 < t) {
      uint2 cu = YQ[(size_t)tid * N + item];
      const int rem2 = t - 4 * tid;
      if (rem2 < 4) {
        if (rem2 == 1)      { cu.x &= 0x0000FFFFu; cu.y = 0u; }
        else if (rem2 == 2) { cu.y = 0u; }
        else                { cu.y &= 0x0000FFFFu; }
      }
      cpack_s[tid] = cu;
    }
    if (tid == 0) item_sh = N;
    __syncthreads();                                   // (C)

    float acc0 = 0.f, acc1 = 0.f;
    if (V != 1) {
      const int nq = (t + 3) >> 2;
      const uint2* Yp = YQ + i0;
      #pragma unroll 4
      for (int q = 0; q < nq; ++q) {
        uint2 cs = cpack_s[q];
        uint4 yv = *(const uint4*)(Yp + (size_t)q * N);
        acc0 = dot2acc(cs.x, yv.x, acc0);
        acc0 = dot2acc(cs.y, yv.y, acc0);
        acc1 = dot2acc(cs.x, yv.z, acc1);
        acc1 = dot2acc(cs.y, yv.w, acc1);
      }
    } else {
      unsigned ka = cpack_s[0].x;                      // keep staging live (rule #17)
      asm volatile("" :: "v"(ka));
    }
    f16x2 kv = bch2(kp);
    const float y0 = ((float)kv[0] - acc0) * rinv;
    const float y1 = ((float)kv[1] - acc1) * rinv;
    p0 = fmaxf(p0 - y0 * y0, 0.f);
    p1 = fmaxf(p1 - y1 * y1, 0.f);
    p_s[i0]     = p0;
    p_s[i0 + 1] = p1;
    unsigned short* Ys = (unsigned short*)YQ;
    const int rem = t & 3;
    const size_t eb = ((size_t)(t >> 2) * N + i0) * 4;
    Ys[eb + rem]     = __half_as_ushort(__float2half(y0));
    Ys[eb + 4 + rem] = __half_as_ushort(__float2half(y1));
  }
}

// ================= Fallback path (R7, proven): CGS2 projector tracking =================
__global__ void __launch_bounds__(NTH)
k_dpp_main(const int* __restrict__ hdr, const float* __restrict__ G,
           const __half* __restrict__ Gh, float* __restrict__ D,
           float* __restrict__ out) {
  __shared__ float p_s[N];
  __shared__ float g_s[KMX];
  __shared__ float part[16 * KMX];
  __shared__ float u_s[KMX];
  __shared__ float wsum_s[16];
  __shared__ int item_sh;

  const int tid  = threadIdx.x;
  const int lane = tid & 63;
  const int wave = tid >> 6;
  const int kk    = hdr[0];
  const int kfull = hdr[1];
  const unsigned kl0 = (unsigned)hdr[2];
  const unsigned kl1 = (unsigned)hdr[3];

  const float fill = (kfull == N) ? 1.0f : 0.0f;
  out[tid] = fill;
  out[tid + NTH] = fill;
  if (kfull == N || kk == 0) return;

  const int kkr = (kk + 15) & ~15;

  {
    float s0a = 0.f, s0b = 0.f, s1a = 0.f, s1b = 0.f;
    const __half* base = Gh + 2 * tid;
    for (int j = 0; j < kkr; j += 4) {
      float2 f0 = __half22float2(*(const __half2*)(base + (j + 0) * N));
      float2 f1 = __half22float2(*(const __half2*)(base + (j + 1) * N));
      float2 f2 = __half22float2(*(const __half2*)(base + (j + 2) * N));
      float2 f3 = __half22float2(*(const __half2*)(base + (j + 3) * N));
      s0a = fmaf(f0.x, f0.x, s0a); s1a = fmaf(f0.y, f0.y, s1a);
      s0b = fmaf(f1.x, f1.x, s0b); s1b = fmaf(f1.y, f1.y, s1b);
      s0a = fmaf(f2.x, f2.x, s0a); s1a = fmaf(f2.y, f2.y, s1a);
      s0b = fmaf(f3.x, f3.x, s0b); s1b = fmaf(f3.y, f3.y, s1b);
    }
    p_s[2 * tid]     = s0a + s0b;
    p_s[2 * tid + 1] = s1a + s1b;
    if (tid < KMX) {
      uint2 fk = tf2x32(kl0, kl1, 0u, (unsigned)tid);
      uint2 ob = tf2x32(fk.x, fk.y, 0u, 0u);
      u_s[tid] = u01(ob.x ^ ob.y);
    }
    if (tid == 0) item_sh = N;
  }
  __syncthreads();

  for (int t = 0; t < kk; ++t) {
    float a  = p_s[2 * tid];
    float b  = p_s[2 * tid + 1];
    float ts = a + b;
    float ws = ts;
    #pragma unroll
    for (int d = 1; d < 64; d <<= 1) {
      float o = __shfl_up(ws, d, 64);
      if (lane >= d) ws += o;
    }
    if (lane == 63) wsum_s[wave] = ws;
    __syncthreads();
    float S = 0.f, base_wave = 0.f;
    #pragma unroll
    for (int w = 0; w < 16; ++w) {
      float wv = wsum_s[w];
      if (w < wave) base_wave += wv;
      S += wv;
    }
    const float u = u_s[t];
    float excl = __shfl_up(ws, 1, 64);
    if (lane == 0) excl = 0.f;
    const float base = base_wave + excl;
    const float c0 = (base + a) / S;
    const float c1 = (base + ts) / S;
    const bool m0 = (u < c0);
    const bool m1 = (u < c1);
    unsigned long long bal = __ballot(m0 || m1);
    if (bal) {
      int first = (int)__builtin_ctzll(bal);
      if (lane == first) atomicMin(&item_sh, m0 ? 2 * tid : 2 * tid + 1);
    }
    __syncthreads();
    int item = item_sh;
    if (item >= N) item = 0;
    if (tid == 0) out[item] = 1.0f;
    if (t == kk - 1) break;

    if (tid < KMX) g_s[tid] = G[tid * N + item];
    __syncthreads();

    {
      float g0 = g_s[lane], g1 = g_s[lane + 64], g2 = g_s[lane + 128];
      float a0 = 0.f, a1 = 0.f, a2 = 0.f;
      for (int s = wave; s < t; s += 16) {
        const float* Dr = D + s * KMX;
        float d0 = Dr[lane], d1 = Dr[lane + 64], d2 = Dr[lane + 128];
        float acc = fmaf(d0, g0, fmaf(d1, g1, d2 * g2));
        #pragma unroll
        for (int m = 1; m < 64; m <<= 1) acc += __shfl_xor(acc, m, 64);
        a0 = fmaf(acc, d0, a0); a1 = fmaf(acc, d1, a1); a2 = fmaf(acc, d2, a2);
      }
      part[wave * KMX + lane]       = a0;
      part[wave * KMX + lane + 64]  = a1;
      part[wave * KMX + lane + 128] = a2;
    }
    __syncthreads();
    if (tid < KMX) {
      float gg = g_s[tid];
      #pragma unroll
      for (int w = 0; w < 16; ++w) gg -= part[w * KMX + tid];
      g_s[tid] = gg;
    }
    __syncthreads();

    float gg2 = 0.f;
    {
      float g0 = g_s[lane], g1 = g_s[lane + 64], g2 = g_s[lane + 128];
      float a0 = 0.f, a1 = 0.f, a2 = 0.f;
      for (int s = wave; s < t; s += 16) {
        const float* Dr = D + s * KMX;
        float d0 = Dr[lane], d1 = Dr[lane + 64], d2 = Dr[lane + 128];
        float acc = fmaf(d0, g0, fmaf(d1, g1, d2 * g2));
        #pragma unroll
        for (int m = 1; m < 64; m <<= 1) acc += __shfl_xor(acc, m, 64);
        a0 = fmaf(acc, d0, a0); a1 = fmaf(acc, d1, a1); a2 = fmaf(acc, d2, a2);
      }
      part[wave * KMX + lane]       = a0;
      part[wave * KMX + lane + 64]  = a1;
      part[wave * KMX + lane + 128] = a2;
    }
    __syncthreads();
    if (tid < KMX) {
      float gg = g_s[tid];
      #pragma unroll
      for (int w = 0; w < 16; ++w) gg -= part[w * KMX + tid];
      gg2 = gg;
    }
    if (wave < 3) {
      float r = gg2 * gg2;
      #pragma unroll
      for (int m = 1; m < 64; m <<= 1) r += __shfl_xor(r, m, 64);
      if (lane == 0) wsum_s[wave] = r;
    }
    __syncthreads();
    const float rho = sqrtf(wsum_s[0] + wsum_s[1] + wsum_s[2]);
    if (tid < KMX) {
      float dj = gg2 / rho;
      g_s[tid] = dj;
      D[t * KMX + tid] = dj;
    }
    if (tid == 0) item_sh = N;
    __syncthreads();

    {
      float s0a = 0.f, s0b = 0.f, s1a = 0.f, s1b = 0.f;
      const __half* base2 = Gh + 2 * tid;
      for (int j = 0; j < kkr; j += 4) {
        float d0 = g_s[j], d1 = g_s[j + 1], d2 = g_s[j + 2], d3 = g_s[j + 3];
        float2 f0 = __half22float2(*(const __half2*)(base2 + (j + 0) * N));
        float2 f1 = __half22float2(*(const __half2*)(base2 + (j + 1) * N));
        float2 f2 = __half22float2(*(const __half2*)(base2 + (j + 2) * N));
        float2 f3 = __half22float2(*(const __half2*)(base2 + (j + 3) * N));
        s0a = fmaf(f0.x, d0, s0a); s1a = fmaf(f0.y, d0, s1a);
        s0b = fmaf(f1.x, d1, s0b); s1b = fmaf(f1.y, d1, s1b);
        s0a = fmaf(f2.x, d2, s0a); s1a = fmaf(f2.y, d2, s1a);
        s0b = fmaf(f3.x, d3, s0b); s1b = fmaf(f3.y, d3, s1b);
      }
      float s0 = s0a + s0b, s1 = s1a + s1b;
      p_s[2 * tid]     = fmaxf(p_s[2 * tid]     - s0 * s0, 0.f);
      p_s[2 * tid + 1] = fmaxf(p_s[2 * tid + 1] - s1 * s1, 0.f);
    }
  }
}

extern "C" void kernel_launch(void* const* d_in, const int* in_sizes, int n_in,
                              void* d_out, int out_size, void* d_ws, size_t ws_size,
                              hipStream_t stream) {
  (void)in_sizes; (void)n_in; (void)out_size;
  const float* e    = (const float*)d_in[0];
  const float* v    = (const float*)d_in[1];
  const int*   seed = (const int*)d_in[2];
  float* out = (float*)d_out;

  int* hdr = (int*)d_ws;
  int* sel = hdr + 8;

  if (ws_size >= (size_t)12 * 1024 * 1024) {
    // Layout: Gh @4KB (768KB); probe-out @1MiB (8KB); YQp @1.25MiB (768KB);
    //         YQ @2.5MiB (768KB); Kh @4MiB (8MB)
    __half* Gh   = (__half*)((char*)d_ws + 4096);
    float*  outp = (float*)((char*)d_ws + (size_t)1024 * 1024);
    uint2*  YQp  = (uint2*)((char*)d_ws + (size_t)1280 * 1024);
    uint2*  YQ   = (uint2*)((char*)d_ws + (size_t)2560 * 1024);
    __half* Kh   = (__half*)((char*)d_ws + (size_t)4096 * 1024);

    k_select<<<1, 256, 0, stream>>>(e, seed, hdr, sel);
    k_gather_h<<<dim3(8, KMX), 256, 0, stream>>>(v, hdr, sel, Gh);
    k_gram<<<dim3(32, 32), 256, 0, stream>>>(Gh, hdr, Kh);
    k_dpp_chol<<<1, NTH, 0, stream>>>(hdr, Kh, YQ, out);
    // ablation probes (scratch output; decomposition via per-dispatch rocprof)
    k_dpp_probe<1><<<1, NTH, 0, stream>>>(hdr, Kh, YQp, outp);
    k_dpp_probe<2><<<1, NTH, 0, stream>>>(hdr, Kh, YQp, outp);
  } else {
    // Proven R7 layout: D @1KB; G f32 @256KB; Gh @2MiB
    float*  D  = (float*)((char*)d_ws + 1024);
    float*  G  = (float*)((char*)d_ws + (size_t)256 * 1024);
    __half* Gh = (__half*)((char*)d_ws + (size_t)2048 * 1024);

    k_select<<<1, 256, 0, stream>>>(e, seed, hdr, sel);
    k_gather<<<dim3(8, KMX), 256, 0, stream>>>(v, hdr, sel, G, Gh);
    k_dpp_main<<<1, NTH, 0, stream>>>(hdr, G, Gh, D, out);
  }
}

// Round 14
// 77.828 us; speedup vs baseline: 1.6842x; 1.6842x over previous
//
#include <hip/hip_runtime.h>
#include <hip/hip_fp16.h>
#include <stdint.h>
#include <stddef.h>

#define N 2048
#define KMX 192
#define NTH 1024
#define PF 12

typedef _Float16 f16x2 __attribute__((ext_vector_type(2)));
typedef _Float16 f16x8 __attribute__((ext_vector_type(8)));
typedef float f32x4 __attribute__((ext_vector_type(4)));

#if defined(__has_builtin)
#if __has_builtin(__builtin_amdgcn_fdot2)
#define HAS_FDOT2 1
#endif
#if __has_builtin(__builtin_amdgcn_mfma_f32_16x16x32_f16)
#define HAS_MFMA16 1
#endif
#endif

__device__ __forceinline__ f16x2 bch2(unsigned u) { return __builtin_bit_cast(f16x2, u); }
__device__ __forceinline__ float dot2acc(unsigned c, unsigned y, float acc) {
#ifdef HAS_FDOT2
  return __builtin_amdgcn_fdot2(bch2(c), bch2(y), acc, false);
#else
  f16x2 cv = bch2(c), yv = bch2(y);
  acc = fmaf((float)cv[0], (float)yv[0], acc);
  acc = fmaf((float)cv[1], (float)yv[1], acc);
  return acc;
#endif
}

// ---------------- Threefry-2x32, JAX-compatible (20 rounds) ----------------
__device__ __forceinline__ void tfround(unsigned &x0, unsigned &x1, const int d) {
  x0 += x1;
  x1 = (x1 << d) | (x1 >> (32 - d));
  x1 ^= x0;
}

__device__ __forceinline__ uint2 tf2x32(unsigned k0, unsigned k1, unsigned c0, unsigned c1) {
  unsigned ks2 = k0 ^ k1 ^ 0x1BD11BDAu;
  unsigned x0 = c0 + k0, x1 = c1 + k1;
  tfround(x0,x1,13); tfround(x0,x1,15); tfround(x0,x1,26); tfround(x0,x1,6);
  x0 += k1;  x1 += ks2 + 1u;
  tfround(x0,x1,17); tfround(x0,x1,29); tfround(x0,x1,16); tfround(x0,x1,24);
  x0 += ks2; x1 += k0 + 2u;
  tfround(x0,x1,13); tfround(x0,x1,15); tfround(x0,x1,26); tfround(x0,x1,6);
  x0 += k0;  x1 += k1 + 3u;
  tfround(x0,x1,17); tfround(x0,x1,29); tfround(x0,x1,16); tfround(x0,x1,24);
  x0 += k1;  x1 += ks2 + 4u;
  tfround(x0,x1,13); tfround(x0,x1,15); tfround(x0,x1,26); tfround(x0,x1,6);
  x0 += ks2; x1 += k0 + 5u;
  uint2 r; r.x = x0; r.y = x1;
  return r;
}

// JAX uniform [0,1): (bits>>9 | 0x3f800000) bitcast - 1.0f  (exact)
__device__ __forceinline__ float u01(unsigned bits) {
  return __uint_as_float((bits >> 9) | 0x3f800000u) - 1.0f;
}

// ---------------- Kernel 1: Bernoulli selection + key derivation ----------------
__global__ void k_select(const float* __restrict__ e, const int* __restrict__ seedp,
                         int* __restrict__ hdr, int* __restrict__ sel) {
  __shared__ unsigned kx0, kx1;
  __shared__ int cnt_s[256];
  __shared__ int pre_s[256];
  const int tid = threadIdx.x;
  if (tid == 0) {
    unsigned seed = (unsigned)seedp[0];
    uint2 kidx  = tf2x32(0u, seed, 0u, 0u);
    uint2 kloop = tf2x32(0u, seed, 0u, 1u);
    kx0 = kidx.x; kx1 = kidx.y;
    hdr[2] = (int)kloop.x;
    hdr[3] = (int)kloop.y;
  }
  __syncthreads();
  const unsigned a0 = kx0, a1 = kx1;
  int flags = 0;
  #pragma unroll
  for (int r = 0; r < 8; ++r) {
    const int i = tid * 8 + r;
    uint2 o = tf2x32(a0, a1, 0u, (unsigned)i);
    float u = u01(o.x ^ o.y);
    float ev = e[i];
    float thr = ev / (ev + 1.0f);   // IEEE f32 div, matches XLA bit-exactly
    if (u < thr) flags |= (1 << r);
  }
  cnt_s[tid] = __popc(flags);
  __syncthreads();
  if (tid == 0) {
    int acc = 0;
    for (int t2 = 0; t2 < 256; ++t2) { pre_s[t2] = acc; acc += cnt_s[t2]; }
    hdr[1] = acc;
    hdr[0] = acc < KMX ? acc : KMX;
  }
  __syncthreads();
  int off = pre_s[tid];
  #pragma unroll
  for (int r = 0; r < 8; ++r) {
    if (flags & (1 << r)) {
      if (off < KMX) sel[off] = tid * 8 + r;
      ++off;
    }
  }
}

// ---------------- Kernel 2 (chol path): gather transposed GhT[i][j] fp16 ----------
// GhT rows are K-contiguous (length KMX) so MFMA A/B fragments load as 16B rows.
__global__ void k_gather_t(const float* __restrict__ v, const int* __restrict__ hdr,
                           const int* __restrict__ sel, __half* __restrict__ GhT) {
  const int j = blockIdx.y;
  const int i = blockIdx.x * 256 + threadIdx.x;
  float val = 0.f;
  if (j < hdr[0]) val = v[(size_t)i * N + sel[j]];
  GhT[(size_t)i * KMX + j] = __float2half(val);
}

// ---------------- Kernel 2 (fallback path): gather G f32 + Gh fp16 mirror ----
__global__ void k_gather(const float* __restrict__ v, const int* __restrict__ hdr,
                         const int* __restrict__ sel, float* __restrict__ G,
                         __half* __restrict__ Gh) {
  const int j = blockIdx.y;
  const int i = blockIdx.x * 256 + threadIdx.x;
  float val = 0.f;
  if (j < hdr[0]) val = v[(size_t)i * N + sel[j]];
  G[j * N + i] = val;
  Gh[j * N + i] = __float2half(val);
}

// ---------------- Kernel 2b: Gram K = GhT · GhT^T via MFMA 16x16x32 f16 ------------
// C[i,i'] = sum_j GhT[i][j]*GhT[i'][j]. A row m = lane&15 (i0 block), B col n =
// lane&15 (i1 block), k = (lane>>4)*8+e (k-permutation cancels between A and B).
// C/D mapping (verified m89): col = lane&15, row = (lane>>4)*4 + reg.
__global__ void __launch_bounds__(256)
k_gram_t(const __half* __restrict__ GhT, __half* __restrict__ Kh) {
#ifdef HAS_MFMA16
  const int tid = threadIdx.x;
  const int l = tid & 63;
  const int w = tid >> 6;
  const int rowBase = blockIdx.y * 64 + w * 16;   // A rows (this wave)
  const int colBase = blockIdx.x * 64;            // B cols (4 sub-tiles of 16)
  const int lr = l & 15;
  const int kg = (l >> 4) * 8;
  f32x4 acc0 = {0.f,0.f,0.f,0.f}, acc1 = {0.f,0.f,0.f,0.f};
  f32x4 acc2 = {0.f,0.f,0.f,0.f}, acc3 = {0.f,0.f,0.f,0.f};
  const __half* Ar = GhT + (size_t)(rowBase + lr) * KMX + kg;
  const __half* Br = GhT + (size_t)(colBase + lr) * KMX + kg;
  #pragma unroll
  for (int j0 = 0; j0 < KMX; j0 += 32) {
    f16x8 a  = *(const f16x8*)(Ar + j0);
    f16x8 b0 = *(const f16x8*)(Br + j0);
    f16x8 b1 = *(const f16x8*)(Br + 16 * KMX + j0);
    f16x8 b2 = *(const f16x8*)(Br + 32 * KMX + j0);
    f16x8 b3 = *(const f16x8*)(Br + 48 * KMX + j0);
    acc0 = __builtin_amdgcn_mfma_f32_16x16x32_f16(a, b0, acc0, 0, 0, 0);
    acc1 = __builtin_amdgcn_mfma_f32_16x16x32_f16(a, b1, acc1, 0, 0, 0);
    acc2 = __builtin_amdgcn_mfma_f32_16x16x32_f16(a, b2, acc2, 0, 0, 0);
    acc3 = __builtin_amdgcn_mfma_f32_16x16x32_f16(a, b3, acc3, 0, 0, 0);
  }
  const int orow = rowBase + (l >> 4) * 4;
  #pragma unroll
  for (int r = 0; r < 4; ++r) {
    __half* Kr = Kh + (size_t)(orow + r) * N + colBase + lr;
    Kr[0]  = __float2half(acc0[r]);
    Kr[16] = __float2half(acc1[r]);
    Kr[32] = __float2half(acc2[r]);
    Kr[48] = __float2half(acc3[r]);
  }
#else
  // scalar fallback (correct, slow): 4x4 outputs per thread
  const int tid = threadIdx.x;
  const int r0 = blockIdx.y * 64 + (tid & 15) * 4;
  const int c0 = blockIdx.x * 64 + (tid >> 4) * 4;
  for (int r = 0; r < 4; ++r)
    for (int c = 0; c < 4; ++c) {
      float acc = 0.f;
      for (int j = 0; j < KMX; ++j)
        acc = fmaf(__half2float(GhT[(size_t)(r0 + r) * KMX + j]),
                   __half2float(GhT[(size_t)(c0 + c) * KMX + j]), acc);
      Kh[(size_t)(r0 + r) * N + c0 + c] = __float2half(acc);
    }
#endif
}

// ---------------- Kernel 3: Cholesky-style sequential DPP loop (quad-packed Y) ------
// y^{(t)}_i = (K[r][i] - sum_{s<t} Y[s][r] Y[s][i]) / sqrt(p_r);  p_i -= y_i^2.
// R13: own-column Y quads (item-independent) are register-prefetched right after
// item is known, so their L2 latency drains WITH the coefficient staging at
// barrier C (T14 issue-early). Scan is then LDS+fdot2-bound for the first PF
// quads; only the t>4*PF tail streams.
__global__ void __launch_bounds__(NTH)
k_dpp_chol(const int* __restrict__ hdr, const __half* __restrict__ Kh,
           uint2* __restrict__ YQ, float* __restrict__ out) {
  __shared__ float p_s[N];
  __shared__ uint2 cpack_s[KMX / 4];   // staged fp16 coefficient quads (masked)
  __shared__ float u_s[KMX];
  __shared__ float wsum_s[16];
  __shared__ int item_sh;

  const int tid  = threadIdx.x;
  const int lane = tid & 63;
  const int wave = tid >> 6;
  const int kk    = hdr[0];
  const int kfull = hdr[1];
  const unsigned kl0 = (unsigned)hdr[2];
  const unsigned kl1 = (unsigned)hdr[3];

  const float fill = (kfull == N) ? 1.0f : 0.0f;   // reference: k==n -> all ones
  out[tid] = fill;
  out[tid + NTH] = fill;
  if (kfull == N || kk == 0) return;

  const int i0 = 2 * tid;

  float p0 = (float)Kh[(size_t)i0 * N + i0];
  float p1 = (float)Kh[(size_t)(i0 + 1) * N + i0 + 1];
  p_s[i0]     = p0;
  p_s[i0 + 1] = p1;
  if (tid < KMX) {
    uint2 fk = tf2x32(kl0, kl1, 0u, (unsigned)tid);
    uint2 ob = tf2x32(fk.x, fk.y, 0u, 0u);
    u_s[tid] = u01(ob.x ^ ob.y);
  }
  if (tid == 0) item_sh = N;
  __syncthreads();

  for (int t = 0; t < kk; ++t) {
    // ---- selection: first i with u < cumsum(p)_i / S ----
    float ts = p0 + p1;
    float ws = ts;
    #pragma unroll
    for (int d = 1; d < 64; d <<= 1) {
      float o = __shfl_up(ws, d, 64);
      if (lane >= d) ws += o;
    }
    if (lane == 63) wsum_s[wave] = ws;
    __syncthreads();                                   // (A)
    float wv = (lane < 16) ? wsum_s[lane] : 0.f;
    #pragma unroll
    for (int d = 1; d < 16; d <<= 1) {
      float o = __shfl_up(wv, d, 16);
      if ((lane & 15) >= d) wv += o;
    }
    const float S    = __shfl(wv, 15, 64);
    const float binc = __shfl(wv, wave, 64);
    const float base_wave = binc - wsum_s[wave];
    const float Sinv = 1.0f / S;
    const float u = u_s[t];
    float excl = __shfl_up(ws, 1, 64);
    if (lane == 0) excl = 0.f;
    const float base = base_wave + excl;
    const float c0 = (base + p0) * Sinv;
    const float c1 = (base + ts) * Sinv;
    const bool m0 = (u < c0);
    const bool m1 = (u < c1);
    unsigned long long bal = __ballot(m0 || m1);
    if (bal) {
      int first = (int)__builtin_ctzll(bal);
      if (lane == first) atomicMin(&item_sh, m0 ? i0 : i0 + 1);
    }
    __syncthreads();                                   // (B)
    int item = item_sh;
    if (item >= N) item = 0;                           // argmax(all False) == 0
    if (tid == 0) out[item] = 1.0f;
    if (t == kk - 1) break;                            // reference: m==1 -> no update

    // ---- issue K-row load + rinv + own-column prefetch (drain together at C) ----
    const unsigned kp = *(const unsigned*)(Kh + (size_t)item * N + i0);
    const float rinv = 1.0f / sqrtf(fmaxf(p_s[item], 1e-30f));
    const int nq = (t + 3) >> 2;
    const uint2* Yp = YQ + i0;
    uint4 pf[PF];
    #pragma unroll
    for (int q = 0; q < PF; ++q)
      if (q < nq) pf[q] = *(const uint4*)(Yp + (size_t)q * N);

    // ---- stage coefficient quads c_q = Y[4q..4q+3][item] into LDS (tail-masked) ----
    if (tid * 4 < t) {
      uint2 cu = YQ[(size_t)tid * N + item];
      const int rem2 = t - 4 * tid;                    // valid slots in this quad (>=1)
      if (rem2 < 4) {
        if (rem2 == 1)      { cu.x &= 0x0000FFFFu; cu.y = 0u; }
        else if (rem2 == 2) { cu.y = 0u; }
        else                { cu.y &= 0x0000FFFFu; }   // rem2 == 3
      }
      cpack_s[tid] = cu;
    }
    if (tid == 0) item_sh = N;                         // reset for next iteration
    __syncthreads();                                   // (C)

    // ---- y = (K_row - Y^T c) * rinv; p -= y^2; append Y slot t ----
    {
      const int npf = nq < PF ? nq : PF;
      float acc0 = 0.f, acc1 = 0.f;
      #pragma unroll
      for (int q = 0; q < PF; ++q) {
        if (q < npf) {
          uint2 cs = cpack_s[q];
          uint4 yv = pf[q];
          acc0 = dot2acc(cs.x, yv.x, acc0);
          acc0 = dot2acc(cs.y, yv.y, acc0);
          acc1 = dot2acc(cs.x, yv.z, acc1);
          acc1 = dot2acc(cs.y, yv.w, acc1);
        }
      }
      for (int q = PF; q < nq; ++q) {                  // streamed tail (t > 4*PF)
        uint2 cs = cpack_s[q];
        uint4 yv = *(const uint4*)(Yp + (size_t)q * N);
        acc0 = dot2acc(cs.x, yv.x, acc0);
        acc0 = dot2acc(cs.y, yv.y, acc0);
        acc1 = dot2acc(cs.x, yv.z, acc1);
        acc1 = dot2acc(cs.y, yv.w, acc1);
      }
      f16x2 kv = bch2(kp);
      const float y0 = ((float)kv[0] - acc0) * rinv;
      const float y1 = ((float)kv[1] - acc1) * rinv;
      p0 = fmaxf(p0 - y0 * y0, 0.f);
      p1 = fmaxf(p1 - y1 * y1, 0.f);
      p_s[i0]     = p0;
      p_s[i0 + 1] = p1;
      unsigned short* Ys = (unsigned short*)YQ;
      const int rem = t & 3;
      const size_t eb = ((size_t)(t >> 2) * N + i0) * 4;
      Ys[eb + rem]     = __half_as_ushort(__float2half(y0));
      Ys[eb + 4 + rem] = __half_as_ushort(__float2half(y1));
    }
    // p_s rows thread-private; item/wsum/cpack hazards ordered by barriers A/B/C.
  }
}

// ================= Fallback path (R7, proven): CGS2 projector tracking =================
__global__ void __launch_bounds__(NTH)
k_dpp_main(const int* __restrict__ hdr, const float* __restrict__ G,
           const __half* __restrict__ Gh, float* __restrict__ D,
           float* __restrict__ out) {
  __shared__ float p_s[N];
  __shared__ float g_s[KMX];
  __shared__ float part[16 * KMX];
  __shared__ float u_s[KMX];
  __shared__ float wsum_s[16];
  __shared__ int item_sh;

  const int tid  = threadIdx.x;
  const int lane = tid & 63;
  const int wave = tid >> 6;
  const int kk    = hdr[0];
  const int kfull = hdr[1];
  const unsigned kl0 = (unsigned)hdr[2];
  const unsigned kl1 = (unsigned)hdr[3];

  const float fill = (kfull == N) ? 1.0f : 0.0f;
  out[tid] = fill;
  out[tid + NTH] = fill;
  if (kfull == N || kk == 0) return;

  const int kkr = (kk + 15) & ~15;

  {
    float s0a = 0.f, s0b = 0.f, s1a = 0.f, s1b = 0.f;
    const __half* base = Gh + 2 * tid;
    for (int j = 0; j < kkr; j += 4) {
      float2 f0 = __half22float2(*(const __half2*)(base + (j + 0) * N));
      float2 f1 = __half22float2(*(const __half2*)(base + (j + 1) * N));
      float2 f2 = __half22float2(*(const __half2*)(base + (j + 2) * N));
      float2 f3 = __half22float2(*(const __half2*)(base + (j + 3) * N));
      s0a = fmaf(f0.x, f0.x, s0a); s1a = fmaf(f0.y, f0.y, s1a);
      s0b = fmaf(f1.x, f1.x, s0b); s1b = fmaf(f1.y, f1.y, s1b);
      s0a = fmaf(f2.x, f2.x, s0a); s1a = fmaf(f2.y, f2.y, s1a);
      s0b = fmaf(f3.x, f3.x, s0b); s1b = fmaf(f3.y, f3.y, s1b);
    }
    p_s[2 * tid]     = s0a + s0b;
    p_s[2 * tid + 1] = s1a + s1b;
    if (tid < KMX) {
      uint2 fk = tf2x32(kl0, kl1, 0u, (unsigned)tid);
      uint2 ob = tf2x32(fk.x, fk.y, 0u, 0u);
      u_s[tid] = u01(ob.x ^ ob.y);
    }
    if (tid == 0) item_sh = N;
  }
  __syncthreads();

  for (int t = 0; t < kk; ++t) {
    float a  = p_s[2 * tid];
    float b  = p_s[2 * tid + 1];
    float ts = a + b;
    float ws = ts;
    #pragma unroll
    for (int d = 1; d < 64; d <<= 1) {
      float o = __shfl_up(ws, d, 64);
      if (lane >= d) ws += o;
    }
    if (lane == 63) wsum_s[wave] = ws;
    __syncthreads();
    float S = 0.f, base_wave = 0.f;
    #pragma unroll
    for (int w = 0; w < 16; ++w) {
      float wv = wsum_s[w];
      if (w < wave) base_wave += wv;
      S += wv;
    }
    const float u = u_s[t];
    float excl = __shfl_up(ws, 1, 64);
    if (lane == 0) excl = 0.f;
    const float base = base_wave + excl;
    const float c0 = (base + a) / S;
    const float c1 = (base + ts) / S;
    const bool m0 = (u < c0);
    const bool m1 = (u < c1);
    unsigned long long bal = __ballot(m0 || m1);
    if (bal) {
      int first = (int)__builtin_ctzll(bal);
      if (lane == first) atomicMin(&item_sh, m0 ? 2 * tid : 2 * tid + 1);
    }
    __syncthreads();
    int item = item_sh;
    if (item >= N) item = 0;
    if (tid == 0) out[item] = 1.0f;
    if (t == kk - 1) break;

    if (tid < KMX) g_s[tid] = G[tid * N + item];
    __syncthreads();

    {
      float g0 = g_s[lane], g1 = g_s[lane + 64], g2 = g_s[lane + 128];
      float a0 = 0.f, a1 = 0.f, a2 = 0.f;
      for (int s = wave; s < t; s += 16) {
        const float* Dr = D + s * KMX;
        float d0 = Dr[lane], d1 = Dr[lane + 64], d2 = Dr[lane + 128];
        float acc = fmaf(d0, g0, fmaf(d1, g1, d2 * g2));
        #pragma unroll
        for (int m = 1; m < 64; m <<= 1) acc += __shfl_xor(acc, m, 64);
        a0 = fmaf(acc, d0, a0); a1 = fmaf(acc, d1, a1); a2 = fmaf(acc, d2, a2);
      }
      part[wave * KMX + lane]       = a0;
      part[wave * KMX + lane + 64]  = a1;
      part[wave * KMX + lane + 128] = a2;
    }
    __syncthreads();
    if (tid < KMX) {
      float gg = g_s[tid];
      #pragma unroll
      for (int w = 0; w < 16; ++w) gg -= part[w * KMX + tid];
      g_s[tid] = gg;
    }
    __syncthreads();

    float gg2 = 0.f;
    {
      float g0 = g_s[lane], g1 = g_s[lane + 64], g2 = g_s[lane + 128];
      float a0 = 0.f, a1 = 0.f, a2 = 0.f;
      for (int s = wave; s < t; s += 16) {
        const float* Dr = D + s * KMX;
        float d0 = Dr[lane], d1 = Dr[lane + 64], d2 = Dr[lane + 128];
        float acc = fmaf(d0, g0, fmaf(d1, g1, d2 * g2));
        #pragma unroll
        for (int m = 1; m < 64; m <<= 1) acc += __shfl_xor(acc, m, 64);
        a0 = fmaf(acc, d0, a0); a1 = fmaf(acc, d1, a1); a2 = fmaf(acc, d2, a2);
      }
      part[wave * KMX + lane]       = a0;
      part[wave * KMX + lane + 64]  = a1;
      part[wave * KMX + lane + 128] = a2;
    }
    __syncthreads();
    if (tid < KMX) {
      float gg = g_s[tid];
      #pragma unroll
      for (int w = 0; w < 16; ++w) gg -= part[w * KMX + tid];
      gg2 = gg;
    }
    if (wave < 3) {
      float r = gg2 * gg2;
      #pragma unroll
      for (int m = 1; m < 64; m <<= 1) r += __shfl_xor(r, m, 64);
      if (lane == 0) wsum_s[wave] = r;
    }
    __syncthreads();
    const float rho = sqrtf(wsum_s[0] + wsum_s[1] + wsum_s[2]);
    if (tid < KMX) {
      float dj = gg2 / rho;
      g_s[tid] = dj;
      D[t * KMX + tid] = dj;
    }
    if (tid == 0) item_sh = N;
    __syncthreads();

    {
      float s0a = 0.f, s0b = 0.f, s1a = 0.f, s1b = 0.f;
      const __half* base2 = Gh + 2 * tid;
      for (int j = 0; j < kkr; j += 4) {
        float d0 = g_s[j], d1 = g_s[j + 1], d2 = g_s[j + 2], d3 = g_s[j + 3];
        float2 f0 = __half22float2(*(const __half2*)(base2 + (j + 0) * N));
        float2 f1 = __half22float2(*(const __half2*)(base2 + (j + 1) * N));
        float2 f2 = __half22float2(*(const __half2*)(base2 + (j + 2) * N));
        float2 f3 = __half22float2(*(const __half2*)(base2 + (j + 3) * N));
        s0a = fmaf(f0.x, d0, s0a); s1a = fmaf(f0.y, d0, s1a);
        s0b = fmaf(f1.x, d1, s0b); s1b = fmaf(f1.y, d1, s1b);
        s0a = fmaf(f2.x, d2, s0a); s1a = fmaf(f2.y, d2, s1a);
        s0b = fmaf(f3.x, d3, s0b); s1b = fmaf(f3.y, d3, s1b);
      }
      float s0 = s0a + s0b, s1 = s1a + s1b;
      p_s[2 * tid]     = fmaxf(p_s[2 * tid]     - s0 * s0, 0.f);
      p_s[2 * tid + 1] = fmaxf(p_s[2 * tid + 1] - s1 * s1, 0.f);
    }
  }
}

extern "C" void kernel_launch(void* const* d_in, const int* in_sizes, int n_in,
                              void* d_out, int out_size, void* d_ws, size_t ws_size,
                              hipStream_t stream) {
  (void)in_sizes; (void)n_in; (void)out_size;
  const float* e    = (const float*)d_in[0];
  const float* v    = (const float*)d_in[1];
  const int*   seed = (const int*)d_in[2];
  float* out = (float*)d_out;

  int* hdr = (int*)d_ws;
  int* sel = hdr + 8;

  if (ws_size >= (size_t)12 * 1024 * 1024) {
    // Layout: GhT @4KB (768KB, [N][KMX] fp16); YQ @2.5MiB (768KB, quad-packed);
    //         Kh @4MiB (8MB)
    __half* GhT = (__half*)((char*)d_ws + 4096);
    uint2*  YQ  = (uint2*)((char*)d_ws + (size_t)2560 * 1024);
    __half* Kh  = (__half*)((char*)d_ws + (size_t)4096 * 1024);

    k_select<<<1, 256, 0, stream>>>(e, seed, hdr, sel);
    k_gather_t<<<dim3(8, KMX), 256, 0, stream>>>(v, hdr, sel, GhT);
    k_gram_t<<<dim3(32, 32), 256, 0, stream>>>(GhT, Kh);
    k_dpp_chol<<<1, NTH, 0, stream>>>(hdr, Kh, YQ, out);
  } else {
    // Proven R7 layout: D @1KB; G f32 @256KB; Gh @2MiB
    float*  D  = (float*)((char*)d_ws + 1024);
    float*  G  = (float*)((char*)d_ws + (size_t)256 * 1024);
    __half* Gh = (__half*)((char*)d_ws + (size_t)2048 * 1024);

    k_select<<<1, 256, 0, stream>>>(e, seed, hdr, sel);
    k_gather<<<dim3(8, KMX), 256, 0, stream>>>(v, hdr, sel, G, Gh);
    k_dpp_main<<<1, NTH, 0, stream>>>(hdr, G, Gh, D, out);
  }
}

// Round 15
// 67.313 us; speedup vs baseline: 1.9473x; 1.1562x over previous
//
#include <hip/hip_runtime.h>
#include <hip/hip_fp16.h>
#include <stdint.h>
#include <stddef.h>

#define N 2048
#define KMX 192
#define NTH 1024

typedef _Float16 f16x2 __attribute__((ext_vector_type(2)));
typedef _Float16 f16x4 __attribute__((ext_vector_type(4)));

#if defined(__has_builtin)
#if __has_builtin(__builtin_amdgcn_fdot2)
#define HAS_FDOT2 1
#endif
#endif

__device__ __forceinline__ f16x2 bch2(unsigned u) { return __builtin_bit_cast(f16x2, u); }
__device__ __forceinline__ unsigned packh2(float a, float b) {
  unsigned ua = (unsigned)__half_as_ushort(__float2half(a));
  unsigned ub = (unsigned)__half_as_ushort(__float2half(b));
  return ua | (ub << 16);
}
__device__ __forceinline__ float dot2acc(unsigned c, unsigned y, float acc) {
#ifdef HAS_FDOT2
  return __builtin_amdgcn_fdot2(bch2(c), bch2(y), acc, false);
#else
  f16x2 cv = bch2(c), yv = bch2(y);
  acc = fmaf((float)cv[0], (float)yv[0], acc);
  acc = fmaf((float)cv[1], (float)yv[1], acc);
  return acc;
#endif
}

// ---------------- Threefry-2x32, JAX-compatible (20 rounds) ----------------
__device__ __forceinline__ void tfround(unsigned &x0, unsigned &x1, const int d) {
  x0 += x1;
  x1 = (x1 << d) | (x1 >> (32 - d));
  x1 ^= x0;
}

__device__ __forceinline__ uint2 tf2x32(unsigned k0, unsigned k1, unsigned c0, unsigned c1) {
  unsigned ks2 = k0 ^ k1 ^ 0x1BD11BDAu;
  unsigned x0 = c0 + k0, x1 = c1 + k1;
  tfround(x0,x1,13); tfround(x0,x1,15); tfround(x0,x1,26); tfround(x0,x1,6);
  x0 += k1;  x1 += ks2 + 1u;
  tfround(x0,x1,17); tfround(x0,x1,29); tfround(x0,x1,16); tfround(x0,x1,24);
  x0 += ks2; x1 += k0 + 2u;
  tfround(x0,x1,13); tfround(x0,x1,15); tfround(x0,x1,26); tfround(x0,x1,6);
  x0 += k0;  x1 += k1 + 3u;
  tfround(x0,x1,17); tfround(x0,x1,29); tfround(x0,x1,16); tfround(x0,x1,24);
  x0 += k1;  x1 += ks2 + 4u;
  tfround(x0,x1,13); tfround(x0,x1,15); tfround(x0,x1,26); tfround(x0,x1,6);
  x0 += ks2; x1 += k0 + 5u;
  uint2 r; r.x = x0; r.y = x1;
  return r;
}

// JAX uniform [0,1): (bits>>9 | 0x3f800000) bitcast - 1.0f  (exact)
__device__ __forceinline__ float u01(unsigned bits) {
  return __uint_as_float((bits >> 9) | 0x3f800000u) - 1.0f;
}

// ---------------- Kernel 1: Bernoulli selection + key derivation ----------------
__global__ void k_select(const float* __restrict__ e, const int* __restrict__ seedp,
                         int* __restrict__ hdr, int* __restrict__ sel) {
  __shared__ unsigned kx0, kx1;
  __shared__ int cnt_s[256];
  __shared__ int pre_s[256];
  const int tid = threadIdx.x;
  if (tid == 0) {
    unsigned seed = (unsigned)seedp[0];
    uint2 kidx  = tf2x32(0u, seed, 0u, 0u);
    uint2 kloop = tf2x32(0u, seed, 0u, 1u);
    kx0 = kidx.x; kx1 = kidx.y;
    hdr[2] = (int)kloop.x;
    hdr[3] = (int)kloop.y;
  }
  __syncthreads();
  const unsigned a0 = kx0, a1 = kx1;
  int flags = 0;
  #pragma unroll
  for (int r = 0; r < 8; ++r) {
    const int i = tid * 8 + r;
    uint2 o = tf2x32(a0, a1, 0u, (unsigned)i);
    float u = u01(o.x ^ o.y);
    float ev = e[i];
    float thr = ev / (ev + 1.0f);   // IEEE f32 div, matches XLA bit-exactly
    if (u < thr) flags |= (1 << r);
  }
  cnt_s[tid] = __popc(flags);
  __syncthreads();
  if (tid == 0) {
    int acc = 0;
    for (int t2 = 0; t2 < 256; ++t2) { pre_s[t2] = acc; acc += cnt_s[t2]; }
    hdr[1] = acc;
    hdr[0] = acc < KMX ? acc : KMX;
  }
  __syncthreads();
  int off = pre_s[tid];
  #pragma unroll
  for (int r = 0; r < 8; ++r) {
    if (flags & (1 << r)) {
      if (off < KMX) sel[off] = tid * 8 + r;
      ++off;
    }
  }
}

// ---------------- Kernel 2 (chol path): gather Gh fp16 only (col-major, zero-pad) ----
__global__ void k_gather_h(const float* __restrict__ v, const int* __restrict__ hdr,
                           const int* __restrict__ sel, __half* __restrict__ Gh) {
  const int j = blockIdx.y;
  const int i = blockIdx.x * 256 + threadIdx.x;
  float val = 0.f;
  if (j < hdr[0]) val = v[(size_t)i * N + sel[j]];
  Gh[j * N + i] = __float2half(val);
}

// ---------------- Kernel 2 (fallback path): gather G f32 + Gh fp16 mirror ----
__global__ void k_gather(const float* __restrict__ v, const int* __restrict__ hdr,
                         const int* __restrict__ sel, float* __restrict__ G,
                         __half* __restrict__ Gh) {
  const int j = blockIdx.y;
  const int i = blockIdx.x * 256 + threadIdx.x;
  float val = 0.f;
  if (j < hdr[0]) val = v[(size_t)i * N + sel[j]];
  G[j * N + i] = val;
  Gh[j * N + i] = __float2half(val);
}

// ---------------- Kernel 2b: Gram K = G^T G (fp16 out, f32 accum), 64x64 tiles ----------
__global__ void __launch_bounds__(256)
k_gram(const __half* __restrict__ Gh, const int* __restrict__ hdr,
       __half* __restrict__ Kh) {
  __shared__ __align__(16) __half As[32][64];
  __shared__ __align__(16) __half Bs[32][64];
  const int tid = threadIdx.x;
  const int i0 = blockIdx.y * 64;   // C rows
  const int i1 = blockIdx.x * 64;   // C cols
  const int tr = tid & 15, tc = tid >> 4;
  const int kk = hdr[0];
  int kc = (kk + 31) & ~31;
  if (kc > KMX) kc = KMX;

  float acc[4][4];
  #pragma unroll
  for (int r = 0; r < 4; ++r)
    #pragma unroll
    for (int c = 0; c < 4; ++c) acc[r][c] = 0.f;

  const int jr = tid >> 3, c8 = (tid & 7) * 8;
  for (int j0 = 0; j0 < kc; j0 += 32) {
    *(uint4*)&As[jr][c8] = *(const uint4*)(Gh + (size_t)(j0 + jr) * N + i0 + c8);
    *(uint4*)&Bs[jr][c8] = *(const uint4*)(Gh + (size_t)(j0 + jr) * N + i1 + c8);
    __syncthreads();
    #pragma unroll 8
    for (int k = 0; k < 32; ++k) {
      f16x4 a4 = *(const f16x4*)&As[k][tr * 4];
      f16x4 b4 = *(const f16x4*)&Bs[k][tc * 4];
      #pragma unroll
      for (int r = 0; r < 4; ++r)
        #pragma unroll
        for (int c = 0; c < 4; ++c)
          acc[r][c] = fmaf((float)a4[r], (float)b4[c], acc[r][c]);
    }
    __syncthreads();
  }
  #pragma unroll
  for (int r = 0; r < 4; ++r) {
    const int row = i0 + tr * 4 + r;
    uint2 w;
    w.x = packh2(acc[r][0], acc[r][1]);
    w.y = packh2(acc[r][2], acc[r][3]);
    *(uint2*)(Kh + (size_t)row * N + i1 + tc * 4) = w;
  }
}

// ---------------- Kernel 3: Cholesky-style sequential DPP loop (quad-packed Y) ------
// y^{(t)}_i = (K[r][i] - sum_{s<t} Y[s][r] Y[s][i]) / sqrt(p_r);  p_i -= y_i^2.
// 3 barriers/iter. Coefficients STAGED into LDS by 48 threads (parallel scattered
// loads drained at barrier C). p lives in registers (LDS copy only for the
// p[item] broadcast); cross-wave prefix via 16-wide shfl scan; K-row load + rinv
// issued right after item is known so latency drains with staging at barrier C.
// (R11 structure — best measured: chol 48.0-48.8 us. R14's T14-prefetch was null:
// 16 waves of TLP already hide the scan's L2 latency; scan is L2-BW-bound.)
__global__ void __launch_bounds__(NTH)
k_dpp_chol(const int* __restrict__ hdr, const __half* __restrict__ Kh,
           uint2* __restrict__ YQ, float* __restrict__ out) {
  __shared__ float p_s[N];
  __shared__ uint2 cpack_s[KMX / 4];   // staged fp16 coefficient quads (masked)
  __shared__ float u_s[KMX];
  __shared__ float wsum_s[16];
  __shared__ int item_sh;

  const int tid  = threadIdx.x;
  const int lane = tid & 63;
  const int wave = tid >> 6;
  const int kk    = hdr[0];
  const int kfull = hdr[1];
  const unsigned kl0 = (unsigned)hdr[2];
  const unsigned kl1 = (unsigned)hdr[3];

  const float fill = (kfull == N) ? 1.0f : 0.0f;   // reference: k==n -> all ones
  out[tid] = fill;
  out[tid + NTH] = fill;
  if (kfull == N || kk == 0) return;

  const int i0 = 2 * tid;

  // ---- init: p from K diagonal (registers + LDS copy); all u_t; item slot ----
  float p0 = (float)Kh[(size_t)i0 * N + i0];
  float p1 = (float)Kh[(size_t)(i0 + 1) * N + i0 + 1];
  p_s[i0]     = p0;
  p_s[i0 + 1] = p1;
  if (tid < KMX) {
    uint2 fk = tf2x32(kl0, kl1, 0u, (unsigned)tid);
    uint2 ob = tf2x32(fk.x, fk.y, 0u, 0u);
    u_s[tid] = u01(ob.x ^ ob.y);
  }
  if (tid == 0) item_sh = N;
  __syncthreads();

  for (int t = 0; t < kk; ++t) {
    // ---- selection: first i with u < cumsum(p)_i / S ----
    float ts = p0 + p1;
    float ws = ts;
    #pragma unroll
    for (int d = 1; d < 64; d <<= 1) {
      float o = __shfl_up(ws, d, 64);
      if (lane >= d) ws += o;
    }
    if (lane == 63) wsum_s[wave] = ws;
    __syncthreads();                                   // (A)
    // cross-wave prefix of the 16 wave sums via 16-wide shfl scan
    float wv = (lane < 16) ? wsum_s[lane] : 0.f;
    #pragma unroll
    for (int d = 1; d < 16; d <<= 1) {
      float o = __shfl_up(wv, d, 16);
      if ((lane & 15) >= d) wv += o;
    }
    const float S    = __shfl(wv, 15, 64);
    const float binc = __shfl(wv, wave, 64);
    const float base_wave = binc - wsum_s[wave];
    const float Sinv = 1.0f / S;
    const float u = u_s[t];
    float excl = __shfl_up(ws, 1, 64);
    if (lane == 0) excl = 0.f;
    const float base = base_wave + excl;
    const float c0 = (base + p0) * Sinv;
    const float c1 = (base + ts) * Sinv;
    const bool m0 = (u < c0);
    const bool m1 = (u < c1);
    unsigned long long bal = __ballot(m0 || m1);
    if (bal) {
      int first = (int)__builtin_ctzll(bal);
      if (lane == first) atomicMin(&item_sh, m0 ? i0 : i0 + 1);
    }
    __syncthreads();                                   // (B)
    int item = item_sh;
    if (item >= N) item = 0;                           // argmax(all False) == 0
    if (tid == 0) out[item] = 1.0f;
    if (t == kk - 1) break;                            // reference: m==1 -> no update

    // ---- issue K-row load + rinv now; latency drains with staging at barrier C ----
    const unsigned kp = *(const unsigned*)(Kh + (size_t)item * N + i0);
    const float rinv = 1.0f / sqrtf(fmaxf(p_s[item], 1e-30f));

    // ---- stage coefficient quads c_q = Y[4q..4q+3][item] into LDS (tail-masked) ----
    if (tid * 4 < t) {
      uint2 cu = YQ[(size_t)tid * N + item];
      const int rem2 = t - 4 * tid;                    // valid slots in this quad (>=1)
      if (rem2 < 4) {
        if (rem2 == 1)      { cu.x &= 0x0000FFFFu; cu.y = 0u; }
        else if (rem2 == 2) { cu.y = 0u; }
        else                { cu.y &= 0x0000FFFFu; }   // rem2 == 3
      }
      cpack_s[tid] = cu;
    }
    if (tid == 0) item_sh = N;                         // reset for next iteration
    __syncthreads();                                   // (C)

    // ---- y = (K_row - Y^T c) * rinv; p -= y^2; append Y slot t ----
    {
      const int nq = (t + 3) >> 2;
      float acc0 = 0.f, acc1 = 0.f;
      const uint2* Yp = YQ + i0;                       // own columns
      #pragma unroll 4
      for (int q = 0; q < nq; ++q) {
        uint2 cs = cpack_s[q];
        uint4 yv = *(const uint4*)(Yp + (size_t)q * N);  // cols i0,i0+1 x 4 hist
        acc0 = dot2acc(cs.x, yv.x, acc0);
        acc0 = dot2acc(cs.y, yv.y, acc0);
        acc1 = dot2acc(cs.x, yv.z, acc1);
        acc1 = dot2acc(cs.y, yv.w, acc1);
      }
      f16x2 kv = bch2(kp);
      const float y0 = ((float)kv[0] - acc0) * rinv;
      const float y1 = ((float)kv[1] - acc1) * rinv;
      p0 = fmaxf(p0 - y0 * y0, 0.f);
      p1 = fmaxf(p1 - y1 * y1, 0.f);
      p_s[i0]     = p0;
      p_s[i0 + 1] = p1;
      unsigned short* Ys = (unsigned short*)YQ;
      const int rem = t & 3;
      const size_t eb = ((size_t)(t >> 2) * N + i0) * 4;  // ushort index of quad elem
      Ys[eb + rem]     = __half_as_ushort(__float2half(y0));
      Ys[eb + 4 + rem] = __half_as_ushort(__float2half(y1));
    }
    // p_s rows thread-private; item/wsum/cpack hazards ordered by barriers A/B/C.
  }
}

// ================= Fallback path (R7, proven): CGS2 projector tracking =================
__global__ void __launch_bounds__(NTH)
k_dpp_main(const int* __restrict__ hdr, const float* __restrict__ G,
           const __half* __restrict__ Gh, float* __restrict__ D,
           float* __restrict__ out) {
  __shared__ float p_s[N];
  __shared__ float g_s[KMX];
  __shared__ float part[16 * KMX];
  __shared__ float u_s[KMX];
  __shared__ float wsum_s[16];
  __shared__ int item_sh;

  const int tid  = threadIdx.x;
  const int lane = tid & 63;
  const int wave = tid >> 6;
  const int kk    = hdr[0];
  const int kfull = hdr[1];
  const unsigned kl0 = (unsigned)hdr[2];
  const unsigned kl1 = (unsigned)hdr[3];

  const float fill = (kfull == N) ? 1.0f : 0.0f;
  out[tid] = fill;
  out[tid + NTH] = fill;
  if (kfull == N || kk == 0) return;

  const int kkr = (kk + 15) & ~15;

  {
    float s0a = 0.f, s0b = 0.f, s1a = 0.f, s1b = 0.f;
    const __half* base = Gh + 2 * tid;
    for (int j = 0; j < kkr; j += 4) {
      float2 f0 = __half22float2(*(const __half2*)(base + (j + 0) * N));
      float2 f1 = __half22float2(*(const __half2*)(base + (j + 1) * N));
      float2 f2 = __half22float2(*(const __half2*)(base + (j + 2) * N));
      float2 f3 = __half22float2(*(const __half2*)(base + (j + 3) * N));
      s0a = fmaf(f0.x, f0.x, s0a); s1a = fmaf(f0.y, f0.y, s1a);
      s0b = fmaf(f1.x, f1.x, s0b); s1b = fmaf(f1.y, f1.y, s1b);
      s0a = fmaf(f2.x, f2.x, s0a); s1a = fmaf(f2.y, f2.y, s1a);
      s0b = fmaf(f3.x, f3.x, s0b); s1b = fmaf(f3.y, f3.y, s1b);
    }
    p_s[2 * tid]     = s0a + s0b;
    p_s[2 * tid + 1] = s1a + s1b;
    if (tid < KMX) {
      uint2 fk = tf2x32(kl0, kl1, 0u, (unsigned)tid);
      uint2 ob = tf2x32(fk.x, fk.y, 0u, 0u);
      u_s[tid] = u01(ob.x ^ ob.y);
    }
    if (tid == 0) item_sh = N;
  }
  __syncthreads();

  for (int t = 0; t < kk; ++t) {
    float a  = p_s[2 * tid];
    float b  = p_s[2 * tid + 1];
    float ts = a + b;
    float ws = ts;
    #pragma unroll
    for (int d = 1; d < 64; d <<= 1) {
      float o = __shfl_up(ws, d, 64);
      if (lane >= d) ws += o;
    }
    if (lane == 63) wsum_s[wave] = ws;
    __syncthreads();
    float S = 0.f, base_wave = 0.f;
    #pragma unroll
    for (int w = 0; w < 16; ++w) {
      float wv = wsum_s[w];
      if (w < wave) base_wave += wv;
      S += wv;
    }
    const float u = u_s[t];
    float excl = __shfl_up(ws, 1, 64);
    if (lane == 0) excl = 0.f;
    const float base = base_wave + excl;
    const float c0 = (base + a) / S;
    const float c1 = (base + ts) / S;
    const bool m0 = (u < c0);
    const bool m1 = (u < c1);
    unsigned long long bal = __ballot(m0 || m1);
    if (bal) {
      int first = (int)__builtin_ctzll(bal);
      if (lane == first) atomicMin(&item_sh, m0 ? 2 * tid : 2 * tid + 1);
    }
    __syncthreads();
    int item = item_sh;
    if (item >= N) item = 0;
    if (tid == 0) out[item] = 1.0f;
    if (t == kk - 1) break;

    if (tid < KMX) g_s[tid] = G[tid * N + item];
    __syncthreads();

    {
      float g0 = g_s[lane], g1 = g_s[lane + 64], g2 = g_s[lane + 128];
      float a0 = 0.f, a1 = 0.f, a2 = 0.f;
      for (int s = wave; s < t; s += 16) {
        const float* Dr = D + s * KMX;
        float d0 = Dr[lane], d1 = Dr[lane + 64], d2 = Dr[lane + 128];
        float acc = fmaf(d0, g0, fmaf(d1, g1, d2 * g2));
        #pragma unroll
        for (int m = 1; m < 64; m <<= 1) acc += __shfl_xor(acc, m, 64);
        a0 = fmaf(acc, d0, a0); a1 = fmaf(acc, d1, a1); a2 = fmaf(acc, d2, a2);
      }
      part[wave * KMX + lane]       = a0;
      part[wave * KMX + lane + 64]  = a1;
      part[wave * KMX + lane + 128] = a2;
    }
    __syncthreads();
    if (tid < KMX) {
      float gg = g_s[tid];
      #pragma unroll
      for (int w = 0; w < 16; ++w) gg -= part[w * KMX + tid];
      g_s[tid] = gg;
    }
    __syncthreads();

    float gg2 = 0.f;
    {
      float g0 = g_s[lane], g1 = g_s[lane + 64], g2 = g_s[lane + 128];
      float a0 = 0.f, a1 = 0.f, a2 = 0.f;
      for (int s = wave; s < t; s += 16) {
        const float* Dr = D + s * KMX;
        float d0 = Dr[lane], d1 = Dr[lane + 64], d2 = Dr[lane + 128];
        float acc = fmaf(d0, g0, fmaf(d1, g1, d2 * g2));
        #pragma unroll
        for (int m = 1; m < 64; m <<= 1) acc += __shfl_xor(acc, m, 64);
        a0 = fmaf(acc, d0, a0); a1 = fmaf(acc, d1, a1); a2 = fmaf(acc, d2, a2);
      }
      part[wave * KMX + lane]       = a0;
      part[wave * KMX + lane + 64]  = a1;
      part[wave * KMX + lane + 128] = a2;
    }
    __syncthreads();
    if (tid < KMX) {
      float gg = g_s[tid];
      #pragma unroll
      for (int w = 0; w < 16; ++w) gg -= part[w * KMX + tid];
      gg2 = gg;
    }
    if (wave < 3) {
      float r = gg2 * gg2;
      #pragma unroll
      for (int m = 1; m < 64; m <<= 1) r += __shfl_xor(r, m, 64);
      if (lane == 0) wsum_s[wave] = r;
    }
    __syncthreads();
    const float rho = sqrtf(wsum_s[0] + wsum_s[1] + wsum_s[2]);
    if (tid < KMX) {
      float dj = gg2 / rho;
      g_s[tid] = dj;
      D[t * KMX + tid] = dj;
    }
    if (tid == 0) item_sh = N;
    __syncthreads();

    {
      float s0a = 0.f, s0b = 0.f, s1a = 0.f, s1b = 0.f;
      const __half* base2 = Gh + 2 * tid;
      for (int j = 0; j < kkr; j += 4) {
        float d0 = g_s[j], d1 = g_s[j + 1], d2 = g_s[j + 2], d3 = g_s[j + 3];
        float2 f0 = __half22float2(*(const __half2*)(base2 + (j + 0) * N));
        float2 f1 = __half22float2(*(const __half2*)(base2 + (j + 1) * N));
        float2 f2 = __half22float2(*(const __half2*)(base2 + (j + 2) * N));
        float2 f3 = __half22float2(*(const __half2*)(base2 + (j + 3) * N));
        s0a = fmaf(f0.x, d0, s0a); s1a = fmaf(f0.y, d0, s1a);
        s0b = fmaf(f1.x, d1, s0b); s1b = fmaf(f1.y, d1, s1b);
        s0a = fmaf(f2.x, d2, s0a); s1a = fmaf(f2.y, d2, s1a);
        s0b = fmaf(f3.x, d3, s0b); s1b = fmaf(f3.y, d3, s1b);
      }
      float s0 = s0a + s0b, s1 = s1a + s1b;
      p_s[2 * tid]     = fmaxf(p_s[2 * tid]     - s0 * s0, 0.f);
      p_s[2 * tid + 1] = fmaxf(p_s[2 * tid + 1] - s1 * s1, 0.f);
    }
  }
}

extern "C" void kernel_launch(void* const* d_in, const int* in_sizes, int n_in,
                              void* d_out, int out_size, void* d_ws, size_t ws_size,
                              hipStream_t stream) {
  (void)in_sizes; (void)n_in; (void)out_size;
  const float* e    = (const float*)d_in[0];
  const float* v    = (const float*)d_in[1];
  const int*   seed = (const int*)d_in[2];
  float* out = (float*)d_out;

  int* hdr = (int*)d_ws;
  int* sel = hdr + 8;

  if (ws_size >= (size_t)12 * 1024 * 1024) {
    // Layout: Gh @4KB (768KB); YQ @2.5MiB (768KB, quad-packed); Kh @4MiB (8MB)
    __half* Gh = (__half*)((char*)d_ws + 4096);
    uint2*  YQ = (uint2*)((char*)d_ws + (size_t)2560 * 1024);
    __half* Kh = (__half*)((char*)d_ws + (size_t)4096 * 1024);

    k_select<<<1, 256, 0, stream>>>(e, seed, hdr, sel);
    k_gather_h<<<dim3(8, KMX), 256, 0, stream>>>(v, hdr, sel, Gh);
    k_gram<<<dim3(32, 32), 256, 0, stream>>>(Gh, hdr, Kh);
    k_dpp_chol<<<1, NTH, 0, stream>>>(hdr, Kh, YQ, out);
  } else {
    // Proven R7 layout: D @1KB; G f32 @256KB; Gh @2MiB
    float*  D  = (float*)((char*)d_ws + 1024);
    float*  G  = (float*)((char*)d_ws + (size_t)256 * 1024);
    __half* Gh = (__half*)((char*)d_ws + (size_t)2048 * 1024);

    k_select<<<1, 256, 0, stream>>>(e, seed, hdr, sel);
    k_gather<<<dim3(8, KMX), 256, 0, stream>>>(v, hdr, sel, G, Gh);
    k_dpp_main<<<1, NTH, 0, stream>>>(hdr, G, Gh, D, out);
  }
}